// Round 3
// baseline (195.211 us; speedup 1.0000x reference)
//
#include <hip/hip_runtime.h>

// Problem constants (from setup_inputs)
constexpr int NROIS = 2000;
constexpr int Hh = 100, Ww = 100, Cc = 256;
constexpr int CH = 7, CW = 7;
constexpr int C4 = Cc / 4;        // 64 float4 per pixel -> one wave per output pixel
constexpr int NPIX = NROIS * CH * CW;       // 98,000 output pixels
constexpr int NBLK = NPIX / 4;              // 24,500 blocks (4 waves = 4 pixels each)
constexpr int NXCD = 8;
constexpr int CHUNK_Q = NBLK / NXCD;        // 3062
constexpr int CHUNK_R = NBLK % NXCD;        // 4

typedef float floatx4 __attribute__((ext_vector_type(4)));

// ---------------------------------------------------------------------------
// Prepass: counting-sort the 2000 ROIs by (image, y-band) into perm[].
// Intra-bucket order is race-dependent but the result is always a valid
// permutation, and output correctness is order-independent (each ROI writes
// only its own out[n] slice).
// ---------------------------------------------------------------------------
constexpr int NBUCKET = 64;   // 8 images x 8 y-bands (12.5 rows/band)

__global__ __launch_bounds__(256) void roi_bucket_kernel(
    const float* __restrict__ rois, int* __restrict__ perm)
{
    __shared__ int cnt[NBUCKET];
    __shared__ int offs[NBUCKET];
    int t = threadIdx.x;
    if (t < NBUCKET) cnt[t] = 0;
    __syncthreads();

    for (int n = t; n < NROIS; n += 256) {
        const float* r = rois + (size_t)n * 5;
        int   b    = (int)r[0];
        float cy   = 0.5f * (r[2] + r[4]);                 // pixel units [0,100]
        int   band = min(7, max(0, (int)(cy * (8.0f / 100.0f))));
        atomicAdd(&cnt[b * 8 + band], 1);
    }
    __syncthreads();
    if (t == 0) {
        int s = 0;
        for (int k = 0; k < NBUCKET; ++k) { offs[k] = s; s += cnt[k]; }
    }
    __syncthreads();
    for (int n = t; n < NROIS; n += 256) {
        const float* r = rois + (size_t)n * 5;
        int   b    = (int)r[0];
        float cy   = 0.5f * (r[2] + r[4]);
        int   band = min(7, max(0, (int)(cy * (8.0f / 100.0f))));
        int   pos  = atomicAdd(&offs[b * 8 + band], 1);
        perm[pos]  = n;
    }
}

// ---------------------------------------------------------------------------
// Main kernel. Work is enumerated in SORTED roi order; a bijective XCD
// swizzle (blocks dispatch round-robin over 8 XCDs by blockIdx%8) gives each
// XCD a contiguous chunk of sorted work => each XCD sweeps ~1 image in
// y-order, active L2 window ~1-3 MB < 4 MiB per-XCD L2. The 4.9x cross-ROI
// pixel reuse then hits in L2 instead of going to MALL/HBM.
// ---------------------------------------------------------------------------
__global__ __launch_bounds__(256) void roi_crop_resize_kernel(
    const float* __restrict__ fm,    // [B, H, W, C]
    const float* __restrict__ rois,  // [N, 5] = (bidx, x1, y1, x2, y2) pixel units
    const int*   __restrict__ perm,  // [N] sorted-slot -> original roi index
    float* __restrict__ out)         // [N, 7, 7, C]
{
    // Bijective XCD-chunk swizzle (m204 formula): xcd = b%8 gets chunk
    // [start(xcd), start(xcd)+size(xcd)) of the sorted work space.
    int blk  = blockIdx.x;
    int xcd  = blk & (NXCD - 1);
    int slot = blk >> 3;
    int work = (xcd < CHUNK_R ? xcd * (CHUNK_Q + 1)
                              : CHUNK_R * (CHUNK_Q + 1) + (xcd - CHUNK_R) * CHUNK_Q)
             + slot;

    int g  = work * 4 + (threadIdx.x >> 6);     // sorted-space output pixel
    int c4 = threadIdx.x & (C4 - 1);            // lane -> channel group

    int s   = g / 49;                           // sorted roi slot
    int pix = g - s * 49;
    int i   = pix / 7;
    int j   = pix - i * 7;
    int n   = perm[s];                          // original roi index (wave-uniform)

    const float* r = rois + (size_t)n * 5;
    int   b  = (int)r[0];
    // Match reference math order: normalize by /W,/H then *(dim-1)
    float x1 = r[1] / (float)Ww;
    float y1 = r[2] / (float)Hh;
    float x2 = r[3] / (float)Ww;
    float y2 = r[4] / (float)Hh;

    float in_y = y1 * (float)(Hh - 1)
               + (float)i * ((y2 - y1) * (float)(Hh - 1) / (float)(CH - 1));
    float in_x = x1 * (float)(Ww - 1)
               + (float)j * ((x2 - x1) * (float)(Ww - 1) / (float)(CW - 1));

    floatx4 o = (floatx4)0.f;

    bool valid = (in_y >= 0.f) && (in_y <= (float)(Hh - 1)) &&
                 (in_x >= 0.f) && (in_x <= (float)(Ww - 1));
    if (valid) {
        float fy = floorf(in_y), fx = floorf(in_x);
        float ly = in_y - fy,    lx = in_x - fx;
        int ty = (int)fy;
        int by = min(Hh - 1, (int)ceilf(in_y));
        int tx = (int)fx;
        int bx = min(Ww - 1, (int)ceilf(in_x));

        const floatx4* fm4 = (const floatx4*)fm;
        size_t base = (size_t)b * Hh * Ww;
        size_t rT = base + (size_t)ty * Ww;
        size_t rB = base + (size_t)by * Ww;

        floatx4 tl = fm4[(rT + tx) * C4 + c4];
        floatx4 tr = fm4[(rT + bx) * C4 + c4];
        floatx4 bl = fm4[(rB + tx) * C4 + c4];
        floatx4 br = fm4[(rB + bx) * C4 + c4];

        floatx4 top = tl + (tr - tl) * lx;
        floatx4 bot = bl + (br - bl) * lx;
        o = top + (bot - top) * ly;
    }
    // nt store: output stream is never re-read; avoid L2 allocation so the
    // per-XCD L2 capacity stays dedicated to the feature-map window.
    floatx4* dst = (floatx4*)out + (size_t)(n * 49 + pix) * C4 + c4;
    __builtin_nontemporal_store(o, dst);
}

extern "C" void kernel_launch(void* const* d_in, const int* in_sizes, int n_in,
                              void* d_out, int out_size, void* d_ws, size_t ws_size,
                              hipStream_t stream) {
    const float* fm   = (const float*)d_in[0];   // [8,100,100,256] fp32
    const float* rois = (const float*)d_in[1];   // [2000,5] fp32
    float* out = (float*)d_out;                  // [2000,7,7,256] fp32
    int*   perm = (int*)d_ws;                    // needs 2000*4 = 8 KB of workspace

    roi_bucket_kernel<<<1, 256, 0, stream>>>(rois, perm);
    roi_crop_resize_kernel<<<NBLK, 256, 0, stream>>>(fm, rois, perm, out);
}

// Round 4
// 189.382 us; speedup vs baseline: 1.0308x; 1.0308x over previous
//
#include <hip/hip_runtime.h>

// Problem constants (from setup_inputs)
constexpr int NROIS = 2000;
constexpr int Hh = 100, Ww = 100, Cc = 256;
constexpr int CH = 7, CW = 7;
constexpr int C4 = Cc / 4;            // 64 float4 per pixel -> one wave-width
constexpr int NROWS = NROIS * CH;     // 14,000 row-waves (wave = one ROI output row)
constexpr int WPB   = 4;              // waves per block (256 threads)
constexpr int NBLK  = NROWS / WPB;    // 3,500 blocks (exact)
constexpr int NXCD  = 8;
constexpr int CHUNK_Q = NBLK / NXCD;  // 437
constexpr int CHUNK_R = NBLK % NXCD;  // 4

typedef float floatx4 __attribute__((ext_vector_type(4)));

// ---------------------------------------------------------------------------
// Prepass: counting-sort the 2000 ROIs by (image, y-band) into perm[].
// Output correctness is order-independent (each ROI writes only its own slice).
// ---------------------------------------------------------------------------
constexpr int NBUCKET = 64;   // 8 images x 8 y-bands

__global__ __launch_bounds__(256) void roi_bucket_kernel(
    const float* __restrict__ rois, int* __restrict__ perm)
{
    __shared__ int cnt[NBUCKET];
    __shared__ int offs[NBUCKET];
    int t = threadIdx.x;
    if (t < NBUCKET) cnt[t] = 0;
    __syncthreads();

    for (int n = t; n < NROIS; n += 256) {
        const float* r = rois + (size_t)n * 5;
        int   b    = (int)r[0];
        float cy   = 0.5f * (r[2] + r[4]);                 // pixel units [0,100]
        int   band = min(7, max(0, (int)(cy * (8.0f / 100.0f))));
        atomicAdd(&cnt[b * 8 + band], 1);
    }
    __syncthreads();
    if (t == 0) {
        int s = 0;
        for (int k = 0; k < NBUCKET; ++k) { offs[k] = s; s += cnt[k]; }
    }
    __syncthreads();
    for (int n = t; n < NROIS; n += 256) {
        const float* r = rois + (size_t)n * 5;
        int   b    = (int)r[0];
        float cy   = 0.5f * (r[2] + r[4]);
        int   band = min(7, max(0, (int)(cy * (8.0f / 100.0f))));
        int   pos  = atomicAdd(&offs[b * 8 + band], 1);
        perm[pos]  = n;
    }
}

// ---------------------------------------------------------------------------
// Main kernel: ONE WAVE PER ROI OUTPUT ROW (7 pixels).
//  - ROI setup (perm load, roi load, 4 IEEE divides, in_y, row pointers) done
//    once per wave instead of once per pixel (was ~650 VALU cyc/pixel).
//  - Unrolled j-loop issues 28 independent 1KB loads per wave (MLP 5 -> ~30).
//  - Branchless clamped addressing; invalid pixels select 0 (in_x/in_y are
//    in-range by construction of setup_inputs, so no wasted fetches).
//  - Sorted ROI order + bijective XCD chunking keeps the 4.9x cross-ROI reuse
//    in per-XCD L2 (proven: FETCH 170 MB -> 64 MB in round 3).
// ---------------------------------------------------------------------------
__global__ __launch_bounds__(256) void roi_crop_resize_kernel(
    const float* __restrict__ fm,    // [B, H, W, C]
    const float* __restrict__ rois,  // [N, 5] = (bidx, x1, y1, x2, y2) pixel units
    const int*   __restrict__ perm,  // [N] sorted-slot -> original roi index
    float* __restrict__ out)         // [N, 7, 7, C]
{
    int blk  = blockIdx.x;
    int xcd  = blk & (NXCD - 1);
    int slot = blk >> 3;
    int work = (xcd < CHUNK_R ? xcd * (CHUNK_Q + 1)
                              : CHUNK_R * (CHUNK_Q + 1) + (xcd - CHUNK_R) * CHUNK_Q)
             + slot;

    int g    = work * WPB + (threadIdx.x >> 6);   // sorted row index [0, 14000)
    int lane = threadIdx.x & (C4 - 1);            // lane -> channel group

    int s = g / 7;                                // sorted roi slot
    int i = g - s * 7;                            // output row within roi
    s = __builtin_amdgcn_readfirstlane(s);        // wave-uniform -> scalar path
    i = __builtin_amdgcn_readfirstlane(i);
    int n = perm[s];                              // original roi index

    const float* r = rois + (size_t)n * 5;
    int   b  = (int)r[0];
    // Match reference math order: normalize by /W,/H then *(dim-1)
    float x1 = r[1] / (float)Ww;
    float y1 = r[2] / (float)Hh;
    float x2 = r[3] / (float)Ww;
    float y2 = r[4] / (float)Hh;

    float in_y = y1 * (float)(Hh - 1)
               + (float)i * ((y2 - y1) * (float)(Hh - 1) / (float)(CH - 1));
    float x0 = x1 * (float)(Ww - 1);
    float sx = (x2 - x1) * (float)(Ww - 1) / (float)(CW - 1);

    bool  vy = (in_y >= 0.f) && (in_y <= (float)(Hh - 1));
    float fy = floorf(in_y);
    float ly = in_y - fy;
    int ty = max(0, min(Hh - 1, (int)fy));
    int by = max(0, min(Hh - 1, (int)ceilf(in_y)));

    const floatx4* fm4 = (const floatx4*)fm;
    const floatx4* pT  = fm4 + (size_t)(b * (Hh * Ww) + ty * Ww) * C4 + lane;
    const floatx4* pB  = fm4 + (size_t)(b * (Hh * Ww) + by * Ww) * C4 + lane;
    floatx4*       po  = (floatx4*)out + (size_t)(n * (CH * CW) + i * CW) * C4 + lane;

#pragma unroll
    for (int j = 0; j < CW; ++j) {
        float in_x = x0 + (float)j * sx;
        bool valid = vy && (in_x >= 0.f) && (in_x <= (float)(Ww - 1));
        float fx = floorf(in_x);
        float lx = in_x - fx;
        int tx = max(0, min(Ww - 1, (int)fx));
        int bx = max(0, min(Ww - 1, (int)ceilf(in_x)));

        floatx4 tl = pT[(size_t)tx * C4];
        floatx4 tr = pT[(size_t)bx * C4];
        floatx4 bl = pB[(size_t)tx * C4];
        floatx4 br = pB[(size_t)bx * C4];

        floatx4 top = tl + (tr - tl) * lx;
        floatx4 bot = bl + (br - bl) * lx;
        floatx4 o   = top + (bot - top) * ly;
        o = valid ? o : (floatx4)0.f;

        // nt store: 98 MB output stream is never re-read; keep L2 for the fm.
        __builtin_nontemporal_store(o, po + (size_t)j * C4);
    }
}

extern "C" void kernel_launch(void* const* d_in, const int* in_sizes, int n_in,
                              void* d_out, int out_size, void* d_ws, size_t ws_size,
                              hipStream_t stream) {
    const float* fm   = (const float*)d_in[0];   // [8,100,100,256] fp32
    const float* rois = (const float*)d_in[1];   // [2000,5] fp32
    float* out = (float*)d_out;                  // [2000,7,7,256] fp32
    int*   perm = (int*)d_ws;                    // 2000*4 = 8 KB of workspace

    roi_bucket_kernel<<<1, 256, 0, stream>>>(rois, perm);
    roi_crop_resize_kernel<<<NBLK, 256, 0, stream>>>(fm, rois, perm, out);
}

// Round 5
// 188.631 us; speedup vs baseline: 1.0349x; 1.0040x over previous
//
#include <hip/hip_runtime.h>

// Problem constants (from setup_inputs)
constexpr int NROIS = 2000;
constexpr int Hh = 100, Ww = 100, Cc = 256;
constexpr int CH = 7, CW = 7;
constexpr int C4 = Cc / 4;              // 64 float4 per pixel -> one wave-width
constexpr int NPIX = NROIS * CH * CW;   // 98,000 output pixels (1 wave each)
constexpr int WPB  = 4;                 // waves per block
constexpr int NBLK = NPIX / WPB;        // 24,500 blocks (exact)
constexpr int NXCD = 8;
constexpr int CHUNK_Q = NBLK / NXCD;    // 3062
constexpr int CHUNK_R = NBLK % NXCD;    // 4

constexpr int ROW_BYTES = Ww * Cc * 4;        // 102,400 B per fm row
constexpr int PIX_BYTES = Cc * 4;             // 1,024 B per fm pixel
constexpr int IMG_BYTES = Hh * ROW_BYTES;     // 10,240,000 B per image
constexpr int OUTROI_BYTES = CH * CW * PIX_BYTES; // 50,176 B per roi output

typedef float floatx4 __attribute__((ext_vector_type(4)));

// ---------------------------------------------------------------------------
// Prepass (1 block): counting-sort ROIs by (image, y-band) AND precompute all
// per-ROI parameters into params[sorted_slot]:
//   P[0]=y0  P[1]=sy  P[2]=x0  P[3]=sx  (in_y = y0 + i*sy, in_x = x0 + j*sx,
//   math order exactly mirrors the reference)   P[4]=fm byte base (int)
//   P[5]=out byte base (int).
// Main kernel then has ZERO divides and no roi/perm indirection.
// ---------------------------------------------------------------------------
constexpr int NBUCKET = 64;   // 8 images x 8 y-bands

__global__ __launch_bounds__(256) void roi_prep_kernel(
    const float* __restrict__ rois, float* __restrict__ params)
{
    __shared__ int cnt[NBUCKET];
    __shared__ int offs[NBUCKET];
    int t = threadIdx.x;
    if (t < NBUCKET) cnt[t] = 0;
    __syncthreads();

    for (int n = t; n < NROIS; n += 256) {
        const float* r = rois + (size_t)n * 5;
        int   b    = (int)r[0];
        float cy   = 0.5f * (r[2] + r[4]);                 // pixel units [0,100]
        int   band = min(7, max(0, (int)(cy * 0.08f)));
        atomicAdd(&cnt[b * 8 + band], 1);
    }
    __syncthreads();
    if (t == 0) {
        int s = 0;
        for (int k = 0; k < NBUCKET; ++k) { offs[k] = s; s += cnt[k]; }
    }
    __syncthreads();
    for (int n = t; n < NROIS; n += 256) {
        const float* r = rois + (size_t)n * 5;
        int   b    = (int)r[0];
        float cy   = 0.5f * (r[2] + r[4]);
        int   band = min(7, max(0, (int)(cy * 0.08f)));
        int   pos  = atomicAdd(&offs[b * 8 + band], 1);

        // Reference math order: normalize by /W,/H (IEEE divide), then *(dim-1)
        float x1 = r[1] / (float)Ww;
        float y1 = r[2] / (float)Hh;
        float x2 = r[3] / (float)Ww;
        float y2 = r[4] / (float)Hh;
        float* P = params + (size_t)pos * 8;
        P[0] = y1 * (float)(Hh - 1);                          // y0
        P[1] = (y2 - y1) * (float)(Hh - 1) / (float)(CH - 1); // sy
        P[2] = x1 * (float)(Ww - 1);                          // x0
        P[3] = (x2 - x1) * (float)(Ww - 1) / (float)(CW - 1); // sx
        ((int*)P)[4] = b * IMG_BYTES;
        ((int*)P)[5] = n * OUTROI_BYTES;
    }
}

// ---------------------------------------------------------------------------
// Main kernel: ONE WAVE PER OUTPUT PIXEL (98k waves, 12 machine fills).
// Minimal dependent chain: uniform 32B param load -> 32-bit coord/addr math
// -> 4 independent 1KB gathers -> bilinear lerp -> nt store.
// Sorted order + bijective XCD chunking keeps cross-ROI reuse in per-XCD L2
// (proven: FETCH 170 MB -> 64 MB).
// ---------------------------------------------------------------------------
__global__ __launch_bounds__(256) void roi_gather_kernel(
    const char* __restrict__ fm,      // [8,100,100,256] fp32 as bytes
    const float* __restrict__ params, // [2000][8] per sorted slot
    char* __restrict__ out)           // [2000,7,7,256] fp32 as bytes
{
    int blk  = blockIdx.x;
    int xcd  = blk & (NXCD - 1);
    int slot = blk >> 3;
    int work = (xcd < CHUNK_R ? xcd * (CHUNK_Q + 1)
                              : CHUNK_R * (CHUNK_Q + 1) + (xcd - CHUNK_R) * CHUNK_Q)
             + slot;

    // Wave-uniform pixel id -> scalar registers
    int g    = __builtin_amdgcn_readfirstlane(work * WPB + (threadIdx.x >> 6));
    int lane = threadIdx.x & (C4 - 1);

    int s   = g / 49;            // sorted roi slot (magic-mul div)
    int pix = g - s * 49;
    int i   = pix / 7;
    int j   = pix - i * 7;

    const float* P = params + (size_t)s * 8;
    float y0 = P[0], sy = P[1], x0 = P[2], sx = P[3];
    int fmbase  = ((const int*)P)[4];
    int outbase = ((const int*)P)[5];

    float in_y = y0 + (float)i * sy;
    float in_x = x0 + (float)j * sx;

    bool valid = (in_y >= 0.f) && (in_y <= (float)(Hh - 1)) &&
                 (in_x >= 0.f) && (in_x <= (float)(Ww - 1));

    float fy = floorf(in_y), fx = floorf(in_x);
    float ly = in_y - fy,    lx = in_x - fx;
    int ty = max(0, min(Hh - 1, (int)fy));
    int by = max(0, min(Hh - 1, (int)ceilf(in_y)));
    int tx = max(0, min(Ww - 1, (int)fx));
    int bx = max(0, min(Ww - 1, (int)ceilf(in_x)));

    int laneoff = lane * 16;
    int rT = fmbase + ty * ROW_BYTES + laneoff;
    int rB = fmbase + by * ROW_BYTES + laneoff;
    int oTX = tx * PIX_BYTES, oBX = bx * PIX_BYTES;

    floatx4 tl = *(const floatx4*)(fm + rT + oTX);
    floatx4 tr = *(const floatx4*)(fm + rT + oBX);
    floatx4 bl = *(const floatx4*)(fm + rB + oTX);
    floatx4 br = *(const floatx4*)(fm + rB + oBX);

    floatx4 top = tl + (tr - tl) * lx;
    floatx4 bot = bl + (br - bl) * lx;
    floatx4 o   = top + (bot - top) * ly;
    o = valid ? o : (floatx4)0.f;

    // nt store: 98 MB output stream is never re-read; keep L2 for the fm.
    __builtin_nontemporal_store(o, (floatx4*)(out + outbase + pix * PIX_BYTES + laneoff));
}

extern "C" void kernel_launch(void* const* d_in, const int* in_sizes, int n_in,
                              void* d_out, int out_size, void* d_ws, size_t ws_size,
                              hipStream_t stream) {
    const float* fm   = (const float*)d_in[0];   // [8,100,100,256] fp32
    const float* rois = (const float*)d_in[1];   // [2000,5] fp32
    char* out = (char*)d_out;                    // [2000,7,7,256] fp32
    float* params = (float*)d_ws;                // 2000*32 B = 64 KB workspace

    roi_prep_kernel<<<1, 256, 0, stream>>>(rois, params);
    roi_gather_kernel<<<NBLK, 256, 0, stream>>>((const char*)fm, params, out);
}